// Round 1
// baseline (125.759 us; speedup 1.0000x reference)
//
#include <hip/hip_runtime.h>

#define NA 8192
#define TILE 128

__global__ __launch_bounds__(TILE) void dftd3_pair_energy(
    const float* __restrict__ pos,
    const float* __restrict__ p_a1, const float* __restrict__ p_a2,
    const float* __restrict__ p_s6, const float* __restrict__ p_s8,
    float* __restrict__ out)
{
    const int ti = blockIdx.x;
    const int tj = blockIdx.y;
    if (tj < ti) return;                 // symmetry: only upper-triangular tile pairs

    __shared__ float4 sj[TILE];
    const int tid = threadIdx.x;

    // stage j-tile positions into LDS (float4-padded for single b128 broadcast reads)
    const int j = tj * TILE + tid;
    sj[tid] = make_float4(pos[3*j+0], pos[3*j+1], pos[3*j+2], 0.0f);

    // this thread's i-atom in registers
    const int i = ti * TILE + tid;
    const float xi = pos[3*i+0];
    const float yi = pos[3*i+1];
    const float zi = pos[3*i+2];

    // uniform scalars (compiler emits s_load)
    const float a1 = p_a1[0], a2 = p_a2[0];
    const float s6 = p_s6[0], s8 = p_s8[0];
    const float tmp  = a1 + a2;
    const float tmp2 = tmp * tmp;
    const float tmp6 = tmp2 * tmp2 * tmp2;
    const float tmp8 = tmp6 * tmp2;
    const float T6 = tmp6 + 1e-12f;      // EPS folded into the constant term
    const float T8 = tmp8 + 1e-12f;
    const float ns6 = -s6, ns8 = -s8;
    const float EPS2 = 1e-24f;           // mask: d2 > EPS^2 (removes self-pairs)

    __syncthreads();

    float acc0 = 0.0f, acc1 = 0.0f;      // two accumulators to shorten the fma chain
    #pragma unroll 16
    for (int jj = 0; jj < TILE; ++jj) {
        float4 p = sj[jj];               // same address across the wave -> LDS broadcast
        float dx = xi - p.x;
        float dy = yi - p.y;
        float dz = zi - p.z;
        float d2 = fmaf(dx, dx, fmaf(dy, dy, dz * dz));
        float d4 = d2 * d2;
        float d6 = d4 * d2;
        float d8 = d4 * d4;
        float A  = d6 + T6;              // d6 + tmp6 + eps
        float B  = d8 + T8;              // d8 + tmp8 + eps
        // -s6/A - s8/B = -(s6*B + s8*A) / (A*B): one rcp instead of two
        float num = fmaf(ns6, B, ns8 * A);
        num = (d2 > EPS2) ? num : 0.0f;  // self-pair mask
        float r = __builtin_amdgcn_rcpf(A * B);   // v_rcp_f32, ~1 ulp
        if (jj & 1) acc1 = fmaf(num, r, acc1);
        else        acc0 = fmaf(num, r, acc0);
    }

    float acc = acc0 + acc1;
    if (ti != tj) acc *= 2.0f;           // off-diagonal tiles count twice (D symmetric)

    // wave64 butterfly reduction
    #pragma unroll
    for (int off = 32; off > 0; off >>= 1)
        acc += __shfl_xor(acc, off, 64);

    if ((tid & 63) == 0)
        atomicAdd(out, acc);             // one atomic per wave (2 per block)
}

extern "C" void kernel_launch(void* const* d_in, const int* in_sizes, int n_in,
                              void* d_out, int out_size, void* d_ws, size_t ws_size,
                              hipStream_t stream) {
    // setup_inputs order: atomic_numbers(0), positions(1), r2r4(2), a1(3), a2(4), s6(5), s8(6)
    const float* pos = (const float*)d_in[1];
    const float* a1  = (const float*)d_in[3];
    const float* a2  = (const float*)d_in[4];
    const float* s6  = (const float*)d_in[5];
    const float* s8  = (const float*)d_in[6];
    float* out = (float*)d_out;

    hipMemsetAsync(out, 0, sizeof(float), stream);  // d_out is poisoned 0xAA each call

    dim3 grid(NA / TILE, NA / TILE);    // 64 x 64; lower triangle exits immediately
    dftd3_pair_energy<<<grid, TILE, 0, stream>>>(pos, a1, a2, s6, s8, out);
}

// Round 2
// 101.535 us; speedup vs baseline: 1.2386x; 1.2386x over previous
//
#include <hip/hip_runtime.h>

#define NA 8192
#define TILE 128
#define NT (NA / TILE)                 // 64 tiles per dimension
#define NBLK (NT * (NT + 1) / 2)       // 2080 upper-triangular tile pairs
#define NSPLIT 4                       // j-loop split factor
#define BLOCK (TILE * NSPLIT)          // 512 threads = 8 waves
#define JPT (TILE / NSPLIT)            // 32 j-iterations per thread
#define S_OF(r) ((r) * NT - (r) * ((r) - 1) / 2)   // tile-pairs before row r

__global__ __launch_bounds__(BLOCK, 8) void dftd3_pair_energy(
    const float* __restrict__ pos,
    const float* __restrict__ p_a1, const float* __restrict__ p_a2,
    const float* __restrict__ p_s6, const float* __restrict__ p_s8,
    float* __restrict__ out)
{
    // ---- decode 1D block index -> upper-triangular (ti, tj), all blocks live
    const int b = blockIdx.x;
    int ti = (int)((2 * NT + 1 - sqrtf((float)((2 * NT + 1) * (2 * NT + 1) - 8 * b))) * 0.5f);
    if (ti > NT - 1) ti = NT - 1;
    if (ti < 0) ti = 0;
    while (S_OF(ti + 1) <= b) ++ti;    // integer fixup for sqrt rounding
    while (S_OF(ti) > b) --ti;
    const int tj = ti + (b - S_OF(ti));

    __shared__ float4 sj[TILE];        // j-tile positions (w unused pad -> b128 broadcast)
    __shared__ float wsum[BLOCK / 64];

    const int tid  = threadIdx.x;
    const int li   = tid & (TILE - 1); // i-atom within tile
    const int part = tid >> 7;         // which quarter of the j-tile (wave-uniform)

    if (tid < TILE) {
        const int j = tj * TILE + tid;
        sj[tid] = make_float4(pos[3 * j + 0], pos[3 * j + 1], pos[3 * j + 2], 0.0f);
    }

    const int i = ti * TILE + li;
    const float xi = pos[3 * i + 0];
    const float yi = pos[3 * i + 1];
    const float zi = pos[3 * i + 2];

    const float a1 = p_a1[0], a2 = p_a2[0];
    const float s6 = p_s6[0], s8 = p_s8[0];
    const float tmp  = a1 + a2;
    const float tmp2 = tmp * tmp;
    const float tmp6 = tmp2 * tmp2 * tmp2;
    const float tmp8 = tmp6 * tmp2;
    const float T6 = tmp6 + 1e-12f;
    const float T8 = tmp8 + 1e-12f;
    const float ns6 = -s6, ns8 = -s8;
    const float EPS2 = 1e-24f;

    __syncthreads();

    float acc0 = 0.0f, acc1 = 0.0f;
    const int j0 = part * JPT;

    auto body = [&](int k, bool masked) {
        float4 p = sj[j0 + k];          // wave-uniform address -> LDS broadcast
        float dx = xi - p.x;
        float dy = yi - p.y;
        float dz = zi - p.z;
        float d2 = fmaf(dx, dx, fmaf(dy, dy, dz * dz));
        float d4 = d2 * d2;
        float d6 = d4 * d2;
        float d8 = d4 * d4;
        float A  = d6 + T6;
        float B  = d8 + T8;
        float num = fmaf(ns6, B, ns8 * A);   // -(s6*B + s8*A)
        if (masked) num = (d2 > EPS2) ? num : 0.0f;  // self-pair mask (diag tiles only)
        float r = __builtin_amdgcn_rcpf(A * B);      // one v_rcp_f32 for both terms
        if (k & 1) acc1 = fmaf(num, r, acc1);
        else       acc0 = fmaf(num, r, acc0);
    };

    if (ti == tj) {
        #pragma unroll 16
        for (int k = 0; k < JPT; ++k) body(k, true);
    } else {
        #pragma unroll 16
        for (int k = 0; k < JPT; ++k) body(k, false);
    }

    float acc = acc0 + acc1;
    if (ti != tj) acc *= 2.0f;         // off-diagonal tile counts for (tj,ti) too

    // ---- wave64 butterfly, then one atomic per block
    #pragma unroll
    for (int off = 32; off > 0; off >>= 1)
        acc += __shfl_xor(acc, off, 64);

    if ((tid & 63) == 0) wsum[tid >> 6] = acc;
    __syncthreads();
    if (tid == 0) {
        float s = 0.0f;
        #pragma unroll
        for (int w = 0; w < BLOCK / 64; ++w) s += wsum[w];
        atomicAdd(out, s);
    }
}

extern "C" void kernel_launch(void* const* d_in, const int* in_sizes, int n_in,
                              void* d_out, int out_size, void* d_ws, size_t ws_size,
                              hipStream_t stream) {
    // setup_inputs order: atomic_numbers(0), positions(1), r2r4(2), a1(3), a2(4), s6(5), s8(6)
    const float* pos = (const float*)d_in[1];
    const float* a1  = (const float*)d_in[3];
    const float* a2  = (const float*)d_in[4];
    const float* s6  = (const float*)d_in[5];
    const float* s8  = (const float*)d_in[6];
    float* out = (float*)d_out;

    hipMemsetAsync(out, 0, sizeof(float), stream);  // d_out re-poisoned each call

    dftd3_pair_energy<<<dim3(NBLK), BLOCK, 0, stream>>>(pos, a1, a2, s6, s8, out);
}

// Round 3
// 95.075 us; speedup vs baseline: 1.3227x; 1.0679x over previous
//
#include <hip/hip_runtime.h>

#define NA 8192
#define TILE 128
#define NT (NA / TILE)                 // 64 tiles per dimension
#define NBLK (NT * (NT + 1) / 2)       // 2080 upper-triangular tile pairs
#define NSPLIT 4                       // j-loop split factor
#define BLOCK (TILE * NSPLIT)          // 512 threads = 8 waves
#define JPT (TILE / NSPLIT)            // 32 j-iterations per thread
#define NSLOT 16                       // atomic salt slots in d_ws
#define S_OF(r) ((r) * NT - (r) * ((r) - 1) / 2)   // tile-pairs before row r

__global__ __launch_bounds__(BLOCK, 8) void dftd3_pair_energy(
    const float* __restrict__ pos,
    const float* __restrict__ p_a1, const float* __restrict__ p_a2,
    const float* __restrict__ p_s6, const float* __restrict__ p_s8,
    float* __restrict__ partial)
{
    // ---- decode 1D block index -> upper-triangular (ti, tj); all blocks live
    const int b = blockIdx.x;
    int ti = (int)((2 * NT + 1 - sqrtf((float)((2 * NT + 1) * (2 * NT + 1) - 8 * b))) * 0.5f);
    if (ti > NT - 1) ti = NT - 1;
    if (ti < 0) ti = 0;
    while (S_OF(ti + 1) <= b) ++ti;
    while (S_OF(ti) > b) --ti;
    const int tj = ti + (b - S_OF(ti));

    const int tid  = threadIdx.x;
    const int li   = tid & (TILE - 1);                          // i-atom within tile
    // wave-uniform j-quarter, forced into an SGPR so j-loads scalarize
    const int part = __builtin_amdgcn_readfirstlane(tid >> 7);

    const int i = ti * TILE + li;
    const float xi = pos[3 * i + 0];
    const float yi = pos[3 * i + 1];
    const float zi = pos[3 * i + 2];

    const float a1 = p_a1[0], a2 = p_a2[0];
    const float s6 = p_s6[0], s8 = p_s8[0];
    const float tmp  = a1 + a2;
    const float tmp2 = tmp * tmp;
    const float tmp6 = tmp2 * tmp2 * tmp2;
    const float tmp8 = tmp6 * tmp2;
    const float T6 = tmp6 + 1e-12f;    // EPS folded into constant term
    const float T8 = tmp8 + 1e-12f;
    const float ns6 = -s6, ns8 = -s8;
    const float EPS2 = 1e-24f;

    // fully uniform base pointer for this wave's j-range -> s_load_dwordx* batches
    const float* __restrict__ pj = pos + 3 * (tj * TILE + part * JPT);

    float acc0 = 0.0f, acc1 = 0.0f;

    auto body = [&](int k, bool masked) {
        float px = pj[3 * k + 0];       // uniform addr: scalar-cache s_load, no LDS
        float py = pj[3 * k + 1];
        float pz = pj[3 * k + 2];
        float dx = xi - px;
        float dy = yi - py;
        float dz = zi - pz;
        float d2 = fmaf(dx, dx, fmaf(dy, dy, dz * dz));
        float d4 = d2 * d2;
        float d6 = d4 * d2;
        float d8 = d4 * d4;
        float A  = d6 + T6;
        float B  = d8 + T8;
        float num = fmaf(ns6, B, ns8 * A);           // -(s6*B + s8*A)
        if (masked) num = (d2 > EPS2) ? num : 0.0f;  // self-pair mask (diag tiles only)
        float r = __builtin_amdgcn_rcpf(A * B);      // one v_rcp_f32 for both terms
        if (k & 1) acc1 = fmaf(num, r, acc1);
        else       acc0 = fmaf(num, r, acc0);
    };

    if (ti == tj) {
        #pragma unroll 8
        for (int k = 0; k < JPT; ++k) body(k, true);
    } else {
        #pragma unroll 8
        for (int k = 0; k < JPT; ++k) body(k, false);
    }

    float acc = acc0 + acc1;
    if (ti != tj) acc *= 2.0f;         // off-diagonal tile counts for (tj,ti) too

    // ---- wave64 butterfly, then block partial, then salted atomic
    #pragma unroll
    for (int off = 32; off > 0; off >>= 1)
        acc += __shfl_xor(acc, off, 64);

    __shared__ float wsum[BLOCK / 64];
    if ((tid & 63) == 0) wsum[tid >> 6] = acc;
    __syncthreads();
    if (tid == 0) {
        float s = 0.0f;
        #pragma unroll
        for (int w = 0; w < BLOCK / 64; ++w) s += wsum[w];
        atomicAdd(&partial[b & (NSLOT - 1)], s);   // 16 slots: ~130 atomics/line
    }
}

__global__ void reduce_slots(const float* __restrict__ partial, float* __restrict__ out)
{
    if (threadIdx.x == 0) {
        float s = 0.0f;
        #pragma unroll
        for (int k = 0; k < NSLOT; ++k) s += partial[k];
        out[0] = s;
    }
}

extern "C" void kernel_launch(void* const* d_in, const int* in_sizes, int n_in,
                              void* d_out, int out_size, void* d_ws, size_t ws_size,
                              hipStream_t stream) {
    // setup_inputs order: atomic_numbers(0), positions(1), r2r4(2), a1(3), a2(4), s6(5), s8(6)
    const float* pos = (const float*)d_in[1];
    const float* a1  = (const float*)d_in[3];
    const float* a2  = (const float*)d_in[4];
    const float* s6  = (const float*)d_in[5];
    const float* s8  = (const float*)d_in[6];
    float* partial = (float*)d_ws;     // 16-float accumulator array
    float* out = (float*)d_out;

    hipMemsetAsync(partial, 0, NSLOT * sizeof(float), stream);  // ws poisoned each call

    dftd3_pair_energy<<<dim3(NBLK), BLOCK, 0, stream>>>(pos, a1, a2, s6, s8, partial);
    reduce_slots<<<1, 64, 0, stream>>>(partial, out);
}

// Round 4
// 94.935 us; speedup vs baseline: 1.3247x; 1.0015x over previous
//
#include <hip/hip_runtime.h>

#define NA 8192
#define WT 64                           // wave-tile edge (one wave = 64 i-atoms x 64 j-atoms)
#define NTW (NA / WT)                   // 128 wave-tiles per dimension
#define NWJOB (NTW * (NTW + 1) / 2)     // 8256 upper-triangular wave-tile pairs
#define WPB 8                           // waves per block
#define BLOCK (WPB * 64)                // 512 threads
#define NBLK (NWJOB / WPB)              // 1032 blocks (divides exactly)
#define NSLOT 64                        // salted partial slots
#define SLOT_STRIDE 16                  // floats -> 64 B, one L2 line per slot
#define S_OF(r) ((r) * NTW - (r) * ((r) - 1) / 2)   // wave-jobs before row r

__device__ __forceinline__ float bcast(float v, int k) {
    return __int_as_float(__builtin_amdgcn_readlane(__float_as_int(v), k));
}

__global__ __launch_bounds__(BLOCK, 8) void dftd3_pair_energy(
    const float* __restrict__ pos,
    const float* __restrict__ p_a1, const float* __restrict__ p_a2,
    const float* __restrict__ p_s6, const float* __restrict__ p_s8,
    float* __restrict__ partial)
{
    const int tid  = threadIdx.x;
    const int lane = tid & 63;
    // global wave-job id, forced scalar so the decode runs on SALU
    const int w = __builtin_amdgcn_readfirstlane(blockIdx.x * WPB + (tid >> 6));

    // ---- decode w -> upper-triangular (wi, wj) over 128x128 wave-tiles
    int wi = (int)((2 * NTW + 1 - sqrtf((float)((2 * NTW + 1) * (2 * NTW + 1) - 8 * w))) * 0.5f);
    if (wi > NTW - 1) wi = NTW - 1;
    if (wi < 0) wi = 0;
    while (S_OF(wi + 1) <= w) ++wi;     // integer fixup for sqrt rounding
    while (S_OF(wi) > w) --wi;
    const int wj = wi + (w - S_OF(wi));

    // ---- this lane's i-atom and j-atom (the ONLY memory reads in the kernel)
    const int i = wi * WT + lane;
    const float xi = pos[3 * i + 0];
    const float yi = pos[3 * i + 1];
    const float zi = pos[3 * i + 2];
    const int j = wj * WT + lane;
    const float vxj = pos[3 * j + 0];   // held in VGPRs, broadcast via readlane below
    const float vyj = pos[3 * j + 1];
    const float vzj = pos[3 * j + 2];

    const float a1 = p_a1[0], a2 = p_a2[0];
    const float s6 = p_s6[0], s8 = p_s8[0];
    const float tmp  = a1 + a2;
    const float tmp2 = tmp * tmp;
    const float tmp6 = tmp2 * tmp2 * tmp2;
    const float tmp8 = tmp6 * tmp2;
    const float T6 = tmp6 + 1e-12f;     // EPS folded into constant term
    const float T8 = tmp8 + 1e-12f;
    const float ns6 = -s6, ns8 = -s8;
    const float EPS2 = 1e-24f;

    float acc0 = 0.0f, acc1 = 0.0f;

    // inner loop: 3 readlane (SALU, overlaps VALU) + ~15 VALU + 1 rcp. No memory.
    auto body = [&](int k, bool masked) {
        float sx = bcast(vxj, k);       // v_readlane_b32 -> SGPR, constant k after unroll
        float sy = bcast(vyj, k);
        float sz = bcast(vzj, k);
        float dx = xi - sx;             // each VALU op reads at most one SGPR: legal
        float dy = yi - sy;
        float dz = zi - sz;
        float d2 = fmaf(dx, dx, fmaf(dy, dy, dz * dz));
        float d4 = d2 * d2;
        float d6 = d4 * d2;
        float d8 = d4 * d4;
        float A  = d6 + T6;
        float B  = d8 + T8;
        float num = fmaf(ns6, B, ns8 * A);           // -(s6*B + s8*A)
        if (masked) num = (d2 > EPS2) ? num : 0.0f;  // self-pair mask (diagonal tiles)
        float r = __builtin_amdgcn_rcpf(A * B);      // one v_rcp_f32 for both terms
        if (k & 1) acc1 = fmaf(num, r, acc1);
        else       acc0 = fmaf(num, r, acc0);
    };

    if (wi == wj) {
        #pragma unroll 8
        for (int k = 0; k < WT; ++k) body(k, true);
    } else {
        #pragma unroll 8
        for (int k = 0; k < WT; ++k) body(k, false);
    }

    float acc = acc0 + acc1;
    if (wi != wj) acc *= 2.0f;          // off-diagonal wave-tile counts for (wj,wi) too

    // ---- wave64 butterfly, block partial, one salted atomic per block
    #pragma unroll
    for (int off = 32; off > 0; off >>= 1)
        acc += __shfl_xor(acc, off, 64);

    __shared__ float wsum[WPB];
    if (lane == 0) wsum[tid >> 6] = acc;
    __syncthreads();
    if (tid == 0) {
        float s = 0.0f;
        #pragma unroll
        for (int q = 0; q < WPB; ++q) s += wsum[q];
        atomicAdd(&partial[(blockIdx.x & (NSLOT - 1)) * SLOT_STRIDE], s);
    }
}

__global__ void reduce_slots(const float* __restrict__ partial, float* __restrict__ out)
{
    if (threadIdx.x == 0) {
        float s = 0.0f;
        #pragma unroll
        for (int k = 0; k < NSLOT; ++k) s += partial[k * SLOT_STRIDE];
        out[0] = s;
    }
}

extern "C" void kernel_launch(void* const* d_in, const int* in_sizes, int n_in,
                              void* d_out, int out_size, void* d_ws, size_t ws_size,
                              hipStream_t stream) {
    // setup_inputs order: atomic_numbers(0), positions(1), r2r4(2), a1(3), a2(4), s6(5), s8(6)
    const float* pos = (const float*)d_in[1];
    const float* a1  = (const float*)d_in[3];
    const float* a2  = (const float*)d_in[4];
    const float* s6  = (const float*)d_in[5];
    const float* s8  = (const float*)d_in[6];
    float* partial = (float*)d_ws;      // NSLOT line-spaced accumulators
    float* out = (float*)d_out;

    hipMemsetAsync(partial, 0, NSLOT * SLOT_STRIDE * sizeof(float), stream);

    dftd3_pair_energy<<<dim3(NBLK), BLOCK, 0, stream>>>(pos, a1, a2, s6, s8, partial);
    reduce_slots<<<1, 64, 0, stream>>>(partial, out);
}

// Round 5
// 87.500 us; speedup vs baseline: 1.4373x; 1.0850x over previous
//
#include <hip/hip_runtime.h>

#define NA 8192
#define IT 128                          // i-atoms per wave-job (2 per lane, packed)
#define JT 64                           // j-atoms per wave-job (1 per lane, readlane-fed)
#define NI (NA / IT)                    // 64 i-tiles
#define NJ (NA / JT)                    // 128 j-tiles
#define NJOB 4160                       // sum_{I=0..63} (128 - 2I) jobs with J >= 2I
#define WPB 8                           // waves per block
#define BLOCK (WPB * 64)                // 512 threads
#define NBLK (NJOB / WPB)               // 520 blocks
#define S_OF(I) ((I) * (129 - (I)))     // jobs before i-tile row I

typedef float v2f __attribute__((ext_vector_type(2)));

__device__ __forceinline__ float bcast(float v, int k) {
    return __int_as_float(__builtin_amdgcn_readlane(__float_as_int(v), k));
}

__global__ __launch_bounds__(BLOCK, 4) void dftd3_pair_energy(
    const float* __restrict__ pos,
    const float* __restrict__ p_a1, const float* __restrict__ p_a2,
    const float* __restrict__ p_s6, const float* __restrict__ p_s8,
    float* __restrict__ partial, int* __restrict__ cnt,
    float* __restrict__ out)
{
    const int tid  = threadIdx.x;
    const int lane = tid & 63;
    // global wave-job id (scalar)
    const int w = __builtin_amdgcn_readfirstlane(blockIdx.x * WPB + (tid >> 6));

    // ---- decode w -> (I, J) with J in [2I, 128); S_OF is monotone on [0,64]
    int I = (int)((129.0f - sqrtf(16641.0f - 4.0f * (float)w)) * 0.5f);
    if (I < 0) I = 0;
    if (I > NI - 1) I = NI - 1;
    while (S_OF(I + 1) <= w) ++I;
    while (S_OF(I) > w) --I;
    const int J = 2 * I + (w - S_OF(I));
    const bool edge = (w - S_OF(I)) < 2;   // J in {2I, 2I+1}: contains j<=i cells

    // ---- this lane's j-atom (broadcast source) and i-atom PAIR (packed float2)
    const int j = J * JT + lane;
    const float vxj = pos[3 * j + 0];
    const float vyj = pos[3 * j + 1];
    const float vzj = pos[3 * j + 2];

    const int i0 = I * IT + 2 * lane;      // lane owns atoms i0, i0+1
    const v2f xi = { pos[3 * i0 + 0], pos[3 * i0 + 3] };
    const v2f yi = { pos[3 * i0 + 1], pos[3 * i0 + 4] };
    const v2f zi = { pos[3 * i0 + 2], pos[3 * i0 + 5] };

    const float a1 = p_a1[0], a2 = p_a2[0];
    const float s6 = p_s6[0], s8 = p_s8[0];
    const float tmp  = a1 + a2;
    const float tmp2 = tmp * tmp;
    const float tmp6 = tmp2 * tmp2 * tmp2;
    const float tmp8 = tmp6 * tmp2;
    const float T6 = tmp6 + 1e-12f;
    const float T8 = tmp8 + 1e-12f;
    const float SC  = 3.5527137e-15f;      // 2^-48 range-scale for the shared rcp
    const float ns6 = -s6 * SC;            // fold scale into the numerator consts
    const float ns8 = -s8 * SC;

    float accx = 0.0f, accy = 0.0f;

    // per iteration: 2 pairs. ~13 pk-VALU + 3 readlane + 1 rcp + ~5 scalar.
    auto body = [&](int k, bool masked) {
        float sx = bcast(vxj, k);          // j-atom k, broadcast (SGPR splat operand)
        float sy = bcast(vyj, k);
        float sz = bcast(vzj, k);
        v2f dx = xi - sx;
        v2f dy = yi - sy;
        v2f dz = zi - sz;
        v2f d2 = __builtin_elementwise_fma(dx, dx,
                 __builtin_elementwise_fma(dy, dy, dz * dz));
        v2f d4 = d2 * d2;
        v2f A  = __builtin_elementwise_fma(d4, d2, (v2f)T6);   // d6 + T6 (fused)
        v2f B  = __builtin_elementwise_fma(d4, d4, (v2f)T8);   // d8 + T8 (fused)
        v2f num = __builtin_elementwise_fma((v2f)ns6, B, (v2f)ns8 * A); // -(s6*B+s8*A)*2^-48
        v2f den = A * B;
        v2f dens = den * (v2f)SC;          // den * 2^-48: keeps the product in range
        float t = dens.x * dens.y;         // in [2e-10, 3.6e27]: safe
        float r = __builtin_amdgcn_rcpf(t);    // ONE rcp for both pairs
        float numx = num.x, numy = num.y;
        if (masked) {                      // edge jobs: count only j>i (excludes self)
            const int jk = J * JT + k;
            numx = (jk > i0)     ? numx : 0.0f;
            numy = (jk > i0 + 1) ? numy : 0.0f;
        }
        // 1/dens.x = dens.y * r ; term = num * 2^-48 / (den * 2^-48) = exact term
        accx = fmaf(numx, dens.y * r, accx);
        accy = fmaf(numy, dens.x * r, accy);
    };

    if (edge) {
        #pragma unroll 8
        for (int k = 0; k < JT; ++k) body(k, true);
    } else {
        #pragma unroll 8
        for (int k = 0; k < JT; ++k) body(k, false);
    }

    float acc = 2.0f * (accx + accy);      // every counted pair stands for (i,j)+(j,i)

    // ---- wave butterfly, block partial
    #pragma unroll
    for (int off = 32; off > 0; off >>= 1)
        acc += __shfl_xor(acc, off, 64);

    __shared__ float wsum[WPB];
    __shared__ int lastflag;
    if (lane == 0) wsum[tid >> 6] = acc;
    __syncthreads();
    if (tid == 0) {
        float s = 0.0f;
        #pragma unroll
        for (int q = 0; q < WPB; ++q) s += wsum[q];
        atomicExch(&partial[blockIdx.x], s);   // device-coherent store of block sum
        __threadfence();                       // release: partial before counter
        int old = atomicAdd(cnt, 1);
        lastflag = (old == NBLK - 1);
    }
    __syncthreads();                           // block-uniform flag
    if (lastflag) {
        __threadfence();                       // acquire
        float s = 0.0f;
        for (int t = tid; t < NBLK; t += BLOCK)
            s += atomicAdd(&partial[t], 0.0f); // coherent read
        #pragma unroll
        for (int off = 32; off > 0; off >>= 1)
            s += __shfl_xor(s, off, 64);
        if (lane == 0) wsum[tid >> 6] = s;
        __syncthreads();
        if (tid == 0) {
            float tot = 0.0f;
            #pragma unroll
            for (int q = 0; q < WPB; ++q) tot += wsum[q];
            out[0] = tot;
        }
    }
}

extern "C" void kernel_launch(void* const* d_in, const int* in_sizes, int n_in,
                              void* d_out, int out_size, void* d_ws, size_t ws_size,
                              hipStream_t stream) {
    // setup_inputs order: atomic_numbers(0), positions(1), r2r4(2), a1(3), a2(4), s6(5), s8(6)
    const float* pos = (const float*)d_in[1];
    const float* a1  = (const float*)d_in[3];
    const float* a2  = (const float*)d_in[4];
    const float* s6  = (const float*)d_in[5];
    const float* s8  = (const float*)d_in[6];
    float* partial = (float*)d_ws;                    // NBLK block sums (plain stores)
    int*   cnt     = (int*)((char*)d_ws + 65536);     // arrival counter
    float* out     = (float*)d_out;

    hipMemsetAsync(cnt, 0, sizeof(int), stream);      // only 4 bytes to init

    dftd3_pair_energy<<<dim3(NBLK), BLOCK, 0, stream>>>(pos, a1, a2, s6, s8,
                                                        partial, cnt, out);
}